// Round 3
// baseline (118.463 us; speedup 1.0000x reference)
//
#include <hip/hip_runtime.h>
#include <hip/hip_bf16.h>

// N=2048, D=768, H=12, Y=64. QK intermediate = [2048][1536] bf16 (Q cols 0..767, K cols 768..1535).
#define NN 2048
#define DD 768
#define HH 12
#define HW 1536
#define SPLITS 4
#define KPW (NN/SPLITS)           // 512 k-rows per split
#define NCH (KPW/64)              // 8 chunks per split
#define NBLK (16*HH*SPLITS)       // 768 attn blocks
#define NROWS (HH*NN)             // 24576 (h,q) rows
#define FINB 24                   // finalizer blocks (1024 rows each)

typedef __attribute__((ext_vector_type(8))) short bf16x8;
typedef __attribute__((ext_vector_type(4))) float f32x4;

// native v_exp_f32 / v_log_f32 (both base-2).
__device__ __forceinline__ float exp2g(float x) { return __builtin_amdgcn_exp2f(x); }
__device__ __forceinline__ float log2g(float x) { return __builtin_amdgcn_logf(x); }

// beta*log2(e) = 0.125*1.4426950408889634 -> scores in base-2 (applied in proj epilogue).
#define QSCALE 0.18033688011112042f

__device__ __forceinline__ unsigned short bfbits(float x) {
  __hip_bfloat16 h = __float2bfloat16(x);
  return *reinterpret_cast<unsigned short*>(&h);
}

// 8 fp32 -> 8 bf16 (RNE) -> one 16B LDS store. (No scale: QSCALE moved to epilogue,
// saving 32 runtime v_mul per thread per K-step in the staging loop.)
__device__ __forceinline__ void cvt_store(__hip_bfloat16* dst, float4 a, float4 b) {
  union { uint4 v; unsigned short s[8]; } u;
  u.s[0] = bfbits(a.x); u.s[1] = bfbits(a.y);
  u.s[2] = bfbits(a.z); u.s[3] = bfbits(a.w);
  u.s[4] = bfbits(b.x); u.s[5] = bfbits(b.y);
  u.s[6] = bfbits(b.z); u.s[7] = bfbits(b.w);
  *reinterpret_cast<uint4*>(dst) = u.v;
}

// ---------------- Kernel 1: fused convert + QK projection GEMM ---------------
// C[2048][1536] = g[2048][768] * [Wq;Wk][1536][768]^T, fp32 read, bf16 convert
// during LDS staging. QSCALE applied to Q columns in the epilogue (fp32 acc).
// 64x64 tile, BK=64, grid (32,24)=768 (3/CU), double-buffered, 1 barrier/kt.
#define LDP 72   // 64 + 8 pad -> 2-way max on frag reads (free, m136)
__global__ __launch_bounds__(256) void proj_kernel(
    const float* __restrict__ g, const float* __restrict__ Wq,
    const float* __restrict__ Wk, __hip_bfloat16* __restrict__ QK,
    float* __restrict__ out, unsigned int* __restrict__ ticket) {
  __shared__ __align__(16) __hip_bfloat16 As[2][64 * LDP];
  __shared__ __align__(16) __hip_bfloat16 Bs[2][64 * LDP];
  // reset scalar output + attn semaphore (visible to attn via end-of-kernel release)
  if (blockIdx.x == 0 && blockIdx.y == 0 && threadIdx.x == 0) {
    out[0] = 0.0f;
    *ticket = 0u;
  }
  const int t = threadIdx.x;
  const int wave = t >> 6, lane = t & 63;
  const int lr = lane & 15, lg = lane >> 4;
  const int wm = wave & 1, wn = wave >> 1;
  const int bm = blockIdx.x, bn = blockIdx.y;
  const int r0 = t >> 3, s0 = (t & 7) * 8;            // staging unit 0 (rows 0..31)
  const int r1 = (t + 256) >> 3;                      // staging unit 1 (rows 32..63)

  // B-tile source: rows 0..767 of the combined W are Wq, 768.. are Wk.
  const float* wsrc = (bn < HH) ? Wq : Wk;
  const int wrow = (bn < HH) ? bn * 64 : (bn - HH) * 64;
  const float oscale = (bn < HH) ? QSCALE : 1.0f;     // epilogue scale (1.0 exact for K)

  const float* ga0 = g + (bm * 64 + r0) * DD + s0;
  const float* ga1 = g + (bm * 64 + r1) * DD + s0;
  const float* gb0 = wsrc + (wrow + r0) * DD + s0;
  const float* gb1 = wsrc + (wrow + r1) * DD + s0;

  f32x4 acc[2][2] = {};

  // prologue: stage kt=0 (fp32 load -> bf16 cvt -> LDS)
  {
    float4 a0 = *reinterpret_cast<const float4*>(ga0);
    float4 a0h = *reinterpret_cast<const float4*>(ga0 + 4);
    float4 a1 = *reinterpret_cast<const float4*>(ga1);
    float4 a1h = *reinterpret_cast<const float4*>(ga1 + 4);
    float4 b0 = *reinterpret_cast<const float4*>(gb0);
    float4 b0h = *reinterpret_cast<const float4*>(gb0 + 4);
    float4 b1 = *reinterpret_cast<const float4*>(gb1);
    float4 b1h = *reinterpret_cast<const float4*>(gb1 + 4);
    cvt_store(&As[0][r0 * LDP + s0], a0, a0h);
    cvt_store(&As[0][r1 * LDP + s0], a1, a1h);
    cvt_store(&Bs[0][r0 * LDP + s0], b0, b0h);
    cvt_store(&Bs[0][r1 * LDP + s0], b1, b1h);
  }
  __syncthreads();

  for (int it = 0; it < 12; ++it) {
    const int cur = it & 1;
    float4 na0, na0h, na1, na1h, nb0, nb0h, nb1, nb1h;
    if (it < 11) {
      const int kt = (it + 1) * 64;
      na0 = *reinterpret_cast<const float4*>(ga0 + kt);
      na0h = *reinterpret_cast<const float4*>(ga0 + kt + 4);
      na1 = *reinterpret_cast<const float4*>(ga1 + kt);
      na1h = *reinterpret_cast<const float4*>(ga1 + kt + 4);
      nb0 = *reinterpret_cast<const float4*>(gb0 + kt);
      nb0h = *reinterpret_cast<const float4*>(gb0 + kt + 4);
      nb1 = *reinterpret_cast<const float4*>(gb1 + kt);
      nb1h = *reinterpret_cast<const float4*>(gb1 + kt + 4);
    }
#pragma unroll
    for (int ks = 0; ks < 2; ++ks) {
      bf16x8 a[2], b[2];
#pragma unroll
      for (int mt = 0; mt < 2; ++mt)
        a[mt] = *reinterpret_cast<const bf16x8*>(&As[cur][(wm * 32 + mt * 16 + lr) * LDP + ks * 32 + lg * 8]);
#pragma unroll
      for (int nt = 0; nt < 2; ++nt)
        b[nt] = *reinterpret_cast<const bf16x8*>(&Bs[cur][(wn * 32 + nt * 16 + lr) * LDP + ks * 32 + lg * 8]);
#pragma unroll
      for (int mt = 0; mt < 2; ++mt)
#pragma unroll
        for (int nt = 0; nt < 2; ++nt)
          acc[mt][nt] = __builtin_amdgcn_mfma_f32_16x16x32_bf16(a[mt], b[nt], acc[mt][nt], 0, 0, 0);
    }
    if (it < 11) {
      cvt_store(&As[cur ^ 1][r0 * LDP + s0], na0, na0h);
      cvt_store(&As[cur ^ 1][r1 * LDP + s0], na1, na1h);
      cvt_store(&Bs[cur ^ 1][r0 * LDP + s0], nb0, nb0h);
      cvt_store(&Bs[cur ^ 1][r1 * LDP + s0], nb1, nb1h);
      __syncthreads();
    }
  }
#pragma unroll
  for (int mt = 0; mt < 2; ++mt) {
    int row = bm * 64 + wm * 32 + mt * 16 + lg * 4;
#pragma unroll
    for (int nt = 0; nt < 2; ++nt) {
      int col = bn * 64 + wn * 32 + nt * 16 + lr;
#pragma unroll
      for (int r = 0; r < 4; ++r)
        QK[(row + r) * HW + col] = __float2bfloat16(acc[mt][nt][r] * oscale);
    }
  }
}

// ---------------- Kernel 2: scores + online LSE + fused split-merge ----------
// grid (16 q-tiles of 128, 12 heads, 4 k-splits) = 768 blocks (3/CU).
// LDS-staged dbuf K (8KB chunks shared by 4 waves, coalesced). After writing
// its (m,l) partials, each block release-fences and bumps a device ticket;
// the last FINB arrivals spin to NBLK, acquire-fence, and merge+sum their
// 1024-row slice — replaces the reduce_kernel launch (stream-K semaphore).
// Deadlock-free: spinners exist only after >=NBLK-FINB blocks retired, so the
// remaining blocks are scheduled; replay-safe: slice index bounded, stale
// ticket values skip finalization without spinning.
#define LDA 72
__global__ __launch_bounds__(256) void attn_kernel(
    const __hip_bfloat16* __restrict__ QK, float2* __restrict__ part,
    float* __restrict__ out, unsigned int* __restrict__ ticket) {
  __shared__ __align__(16) __hip_bfloat16 Ks[2][64 * LDA];
  __shared__ unsigned int s_old;
  __shared__ float wsum[4];
  const int t = threadIdx.x;
  const int wave = t >> 6, lane = t & 63;
  const int lr = lane & 15, lg = lane >> 4;
  const int q0 = blockIdx.x * 128, h = blockIdx.y, sp = blockIdx.z;
  const int k0 = sp * KPW;
  const int r0 = t >> 3, s0 = (t & 7) * 8;            // chunk coords (2/thread)
  const int r1 = (t + 256) >> 3, s1 = s0;
  const int colK = DD + h * 64;

  // Q fragments: 4 direct loads, resident for the whole kernel
  bf16x8 aq[2][2];
#pragma unroll
  for (int mt = 0; mt < 2; ++mt)
#pragma unroll
    for (int z = 0; z < 2; ++z)
      aq[mt][z] = *reinterpret_cast<const bf16x8*>(
          QK + (q0 + wave * 32 + mt * 16 + lr) * HW + h * 64 + z * 32 + lg * 8);

  // prologue: stage chunk 0
  *reinterpret_cast<uint4*>(&Ks[0][r0 * LDA + s0]) =
      *reinterpret_cast<const uint4*>(QK + (k0 + r0) * HW + colK + s0);
  *reinterpret_cast<uint4*>(&Ks[0][r1 * LDA + s1]) =
      *reinterpret_cast<const uint4*>(QK + (k0 + r1) * HW + colK + s1);
  __syncthreads();

  float m[2][4], l[2][4];
#pragma unroll
  for (int mt = 0; mt < 2; ++mt)
#pragma unroll
    for (int r = 0; r < 4; ++r) { m[mt][r] = -3.0e38f; l[mt][r] = 0.0f; }

  for (int ci = 0; ci < NCH; ++ci) {
    const int cur = ci & 1;
    uint4 n0, n1;
    if (ci < NCH - 1) {
      int kc = k0 + (ci + 1) * 64;
      n0 = *reinterpret_cast<const uint4*>(QK + (kc + r0) * HW + colK + s0);
      n1 = *reinterpret_cast<const uint4*>(QK + (kc + r1) * HW + colK + s1);
    }
    bf16x8 b[4][2];
#pragma unroll
    for (int nt = 0; nt < 4; ++nt)
#pragma unroll
      for (int z = 0; z < 2; ++z)
        b[nt][z] = *reinterpret_cast<const bf16x8*>(&Ks[cur][(nt * 16 + lr) * LDA + z * 32 + lg * 8]);

    f32x4 s[2][4] = {};
#pragma unroll
    for (int mt = 0; mt < 2; ++mt)
#pragma unroll
      for (int nt = 0; nt < 4; ++nt)
#pragma unroll
        for (int z = 0; z < 2; ++z)
          s[mt][nt] = __builtin_amdgcn_mfma_f32_16x16x32_bf16(aq[mt][z], b[nt][z], s[mt][nt], 0, 0, 0);

    // per-lane online update (scores already in base-2 units)
#pragma unroll
    for (int mt = 0; mt < 2; ++mt)
#pragma unroll
      for (int r = 0; r < 4; ++r) {
        float v0 = s[mt][0][r], v1 = s[mt][1][r], v2 = s[mt][2][r], v3 = s[mt][3][r];
        float cm = fmaxf(fmaxf(v0, v1), fmaxf(v2, v3));
        float mn = fmaxf(m[mt][r], cm);
        float p = exp2g(v0 - mn) + exp2g(v1 - mn) +
                  exp2g(v2 - mn) + exp2g(v3 - mn);
        l[mt][r] = l[mt][r] * exp2g(m[mt][r] - mn) + p;
        m[mt][r] = mn;
      }
    if (ci < NCH - 1) {
      *reinterpret_cast<uint4*>(&Ks[cur ^ 1][r0 * LDA + s0]) = n0;
      *reinterpret_cast<uint4*>(&Ks[cur ^ 1][r1 * LDA + s1]) = n1;
      __syncthreads();
    }
  }
  // butterfly merge across the 16 lr-lanes (lg bits untouched)
#pragma unroll
  for (int msk = 1; msk <= 8; msk <<= 1) {
#pragma unroll
    for (int mt = 0; mt < 2; ++mt)
#pragma unroll
      for (int r = 0; r < 4; ++r) {
        float mo = __shfl_xor(m[mt][r], msk);
        float lo = __shfl_xor(l[mt][r], msk);
        float mn = fmaxf(m[mt][r], mo);
        l[mt][r] = l[mt][r] * exp2g(m[mt][r] - mn) + lo * exp2g(mo - mn);
        m[mt][r] = mn;
      }
  }
  if (lr == 0) {
#pragma unroll
    for (int mt = 0; mt < 2; ++mt)
#pragma unroll
      for (int r = 0; r < 4; ++r) {
        int q = q0 + wave * 32 + mt * 16 + lg * 4 + r;
        part[(sp * HH + h) * NN + q] = make_float2(m[mt][r], l[mt][r]);
      }
  }

  // ---- fused split-merge + global sum (stream-K semaphore) ----
  __syncthreads();                        // drains vmcnt: all part stores issued+done
  if (t == 0) {
    __threadfence();                      // agent release: flush this XCD's L2
    s_old = atomicAdd(ticket, 1u);
  }
  __syncthreads();
  const unsigned int old = s_old;
  if (old >= (unsigned)(NBLK - FINB) && old < (unsigned)NBLK) {
    if (t == 0) {
      while (atomicAdd(ticket, 0u) < (unsigned)NBLK) __builtin_amdgcn_s_sleep(8);
    }
    __syncthreads();
    __threadfence();                      // agent acquire: invalidate, see all writers
    const int base = (int)(old - (unsigned)(NBLK - FINB)) * 1024;
    float lsum = 0.0f;
#pragma unroll
    for (int i = 0; i < 4; ++i) {
      int row = base + i * 256 + t;       // coalesced: consecutive t -> consecutive rows
      float2 p0 = part[row];
      float2 p1 = part[NROWS + row];
      float2 p2 = part[2 * NROWS + row];
      float2 p3 = part[3 * NROWS + row];
      float mm = fmaxf(fmaxf(p0.x, p1.x), fmaxf(p2.x, p3.x));
      float ll = p0.y * exp2g(p0.x - mm) + p1.y * exp2g(p1.x - mm) +
                 p2.y * exp2g(p2.x - mm) + p3.y * exp2g(p3.x - mm);
      lsum += mm + log2g(ll);             // base-2 lse
    }
#pragma unroll
    for (int msk = 1; msk <= 32; msk <<= 1)
      lsum += __shfl_xor(lsum, msk);
    if (lane == 0) wsum[wave] = lsum;
    __syncthreads();
    if (t == 0)
      atomicAdd(out, -5.545177444479562f * (wsum[0] + wsum[1] + wsum[2] + wsum[3]));
  }
}

// ---------------- launch -----------------------------------------------------
extern "C" void kernel_launch(void* const* d_in, const int* in_sizes, int n_in,
                              void* d_out, int out_size, void* d_ws, size_t ws_size,
                              hipStream_t stream) {
  const float* g  = (const float*)d_in[0];
  const float* Wq = (const float*)d_in[1];
  const float* Wk = (const float*)d_in[2];
  float* out = (float*)d_out;

  __hip_bfloat16* QK = (__hip_bfloat16*)d_ws;                      // [2048][1536] (6.3 MB)
  float2* part = (float2*)((char*)d_ws + (size_t)NN * HW * 2);     // [4][12][2048] (786 KB)
  unsigned int* ticket = (unsigned int*)((char*)d_ws + (size_t)NN * HW * 2
                                         + (size_t)SPLITS * NROWS * sizeof(float2));

  proj_kernel<<<dim3(32, 24), 256, 0, stream>>>(g, Wq, Wk, QK, out, ticket);
  attn_kernel<<<dim3(16, HH, SPLITS), 256, 0, stream>>>(QK, part, out, ticket);
}

// Round 4
// 95.491 us; speedup vs baseline: 1.2406x; 1.2406x over previous
//
#include <hip/hip_runtime.h>
#include <hip/hip_bf16.h>

// N=2048, D=768, H=12, Y=64. QK intermediate = [2048][1536] bf16 (Q cols 0..767, K cols 768..1535).
#define NN 2048
#define DD 768
#define HH 12
#define HW 1536
#define SPLITS 4
#define KPW (NN/SPLITS)           // 512 k-rows per split
#define NCH (KPW/64)              // 8 chunks per split
#define NROWS (HH*NN)             // 24576 (h,q) rows

typedef __attribute__((ext_vector_type(8))) short bf16x8;
typedef __attribute__((ext_vector_type(4))) float f32x4;

// native v_exp_f32 / v_log_f32 (both base-2).
__device__ __forceinline__ float exp2g(float x) { return __builtin_amdgcn_exp2f(x); }
__device__ __forceinline__ float log2g(float x) { return __builtin_amdgcn_logf(x); }

// beta*log2(e) = 0.125*1.4426950408889634 -> scores in base-2 (applied in proj epilogue).
#define QSCALE 0.18033688011112042f

__device__ __forceinline__ unsigned short bfbits(float x) {
  __hip_bfloat16 h = __float2bfloat16(x);
  return *reinterpret_cast<unsigned short*>(&h);
}

// 8 fp32 -> 8 bf16 (RNE) -> one 16B LDS store.
__device__ __forceinline__ void cvt_store(__hip_bfloat16* dst, float4 a, float4 b) {
  union { uint4 v; unsigned short s[8]; } u;
  u.s[0] = bfbits(a.x); u.s[1] = bfbits(a.y);
  u.s[2] = bfbits(a.z); u.s[3] = bfbits(a.w);
  u.s[4] = bfbits(b.x); u.s[5] = bfbits(b.y);
  u.s[6] = bfbits(b.z); u.s[7] = bfbits(b.w);
  *reinterpret_cast<uint4*>(dst) = u.v;
}

// ---------------- Kernel 1: fused convert + QK projection GEMM ---------------
// C[2048][1536] = g[2048][768] * [Wq;Wk][1536][768]^T, fp32 read, bf16 convert
// during LDS staging. QSCALE applied to Q columns in the epilogue (fp32 acc).
// 128x64 tile (A-rows x B-cols), BK=64, 384 blocks, double-buffered, 1 barrier/kt.
// vs R2's 64x64: g re-read 12x (was 24x) -> total staged traffic 147 MB (was 295).
// XCD-contiguous swizzle: each XCD owns 2 bm-rows (768 KB of g, L2-resident) x all bn.
#define LDP 72   // 64 + 8 pad -> 2-way max on frag reads (free, m136)
__global__ __launch_bounds__(256) void proj_kernel(
    const float* __restrict__ g, const float* __restrict__ Wq,
    const float* __restrict__ Wk, __hip_bfloat16* __restrict__ QK,
    float* __restrict__ out) {
  __shared__ __align__(16) __hip_bfloat16 As[2][128 * LDP];   // 36.9 KB
  __shared__ __align__(16) __hip_bfloat16 Bs[2][64 * LDP];    // 18.4 KB
  if (blockIdx.x == 0 && threadIdx.x == 0) out[0] = 0.0f;
  const int t = threadIdx.x;
  const int wave = t >> 6, lane = t & 63;
  const int lr = lane & 15, lg = lane >> 4;
  const int wm = wave & 1, wn = wave >> 1;     // wave -> (64-row half, 32-col half)
  const int bid = blockIdx.x;
  const int swz = (bid & 7) * 48 + (bid >> 3); // 8 XCDs x 48 contiguous blocks
  const int bm = swz / 24, bn = swz % 24;      // bm 0..15 (128 rows), bn 0..23 (64 cols)
  const int rr = t >> 3, ss = (t & 7) * 8;     // staging: 32 rows x 64 cols per unit

  // B-tile source: 24 tiles of 64 W-rows; 0..11 = Wq (epilogue-scaled), 12..23 = Wk.
  const float* wsrc = (bn < HH) ? Wq : Wk;
  const int wrow = (bn < HH) ? bn * 64 : (bn - HH) * 64;
  const float oscale = (bn < HH) ? QSCALE : 1.0f;

  const float* ga = g + (bm * 128 + rr) * DD + ss;       // A units: +u*32*DD, u=0..3
  const float* gb = wsrc + (wrow + rr) * DD + ss;        // B units: +u*32*DD, u=0..1

  f32x4 acc[4][2] = {};

  // prologue: stage kt=0 (fp32 load -> bf16 cvt -> LDS)
  {
#pragma unroll
    for (int u = 0; u < 4; ++u) {
      float4 lo = *reinterpret_cast<const float4*>(ga + u * 32 * DD);
      float4 hi = *reinterpret_cast<const float4*>(ga + u * 32 * DD + 4);
      cvt_store(&As[0][(rr + u * 32) * LDP + ss], lo, hi);
    }
#pragma unroll
    for (int u = 0; u < 2; ++u) {
      float4 lo = *reinterpret_cast<const float4*>(gb + u * 32 * DD);
      float4 hi = *reinterpret_cast<const float4*>(gb + u * 32 * DD + 4);
      cvt_store(&Bs[0][(rr + u * 32) * LDP + ss], lo, hi);
    }
  }
  __syncthreads();

  for (int it = 0; it < 12; ++it) {
    const int cur = it & 1;
    float4 nal[4], nah[4], nbl[2], nbh[2];
    if (it < 11) {
      const int kt = (it + 1) * 64;
#pragma unroll
      for (int u = 0; u < 4; ++u) {
        nal[u] = *reinterpret_cast<const float4*>(ga + u * 32 * DD + kt);
        nah[u] = *reinterpret_cast<const float4*>(ga + u * 32 * DD + kt + 4);
      }
#pragma unroll
      for (int u = 0; u < 2; ++u) {
        nbl[u] = *reinterpret_cast<const float4*>(gb + u * 32 * DD + kt);
        nbh[u] = *reinterpret_cast<const float4*>(gb + u * 32 * DD + kt + 4);
      }
    }
#pragma unroll
    for (int ks = 0; ks < 2; ++ks) {
      bf16x8 a[4], b[2];
#pragma unroll
      for (int mt = 0; mt < 4; ++mt)
        a[mt] = *reinterpret_cast<const bf16x8*>(&As[cur][(wm * 64 + mt * 16 + lr) * LDP + ks * 32 + lg * 8]);
#pragma unroll
      for (int nt = 0; nt < 2; ++nt)
        b[nt] = *reinterpret_cast<const bf16x8*>(&Bs[cur][(wn * 32 + nt * 16 + lr) * LDP + ks * 32 + lg * 8]);
#pragma unroll
      for (int mt = 0; mt < 4; ++mt)
#pragma unroll
        for (int nt = 0; nt < 2; ++nt)
          acc[mt][nt] = __builtin_amdgcn_mfma_f32_16x16x32_bf16(a[mt], b[nt], acc[mt][nt], 0, 0, 0);
    }
    if (it < 11) {
#pragma unroll
      for (int u = 0; u < 4; ++u)
        cvt_store(&As[cur ^ 1][(rr + u * 32) * LDP + ss], nal[u], nah[u]);
#pragma unroll
      for (int u = 0; u < 2; ++u)
        cvt_store(&Bs[cur ^ 1][(rr + u * 32) * LDP + ss], nbl[u], nbh[u]);
      __syncthreads();
    }
  }
#pragma unroll
  for (int mt = 0; mt < 4; ++mt) {
    int row = bm * 128 + wm * 64 + mt * 16 + lg * 4;
#pragma unroll
    for (int nt = 0; nt < 2; ++nt) {
      int col = bn * 64 + wn * 32 + nt * 16 + lr;
#pragma unroll
      for (int r = 0; r < 4; ++r)
        QK[(row + r) * HW + col] = __float2bfloat16(acc[mt][nt][r] * oscale);
    }
  }
}

// ---------------- Kernel 2: scores + per-lane online LSE, dbuf K in LDS ------
// (verbatim R2: LDS staging loads each 8KB K-chunk ONCE per block fully
// coalesced, shared by 4 waves. No device fences / semaphores — R3's per-block
// __threadfence caused a ~45us L2-writeback storm.)
// grid (16 q-tiles of 128, 12 heads, 4 k-splits) = 768 blocks (3/CU).
#define LDA 72
__global__ __launch_bounds__(256) void attn_kernel(
    const __hip_bfloat16* __restrict__ QK, float2* __restrict__ part) {
  __shared__ __align__(16) __hip_bfloat16 Ks[2][64 * LDA];
  const int t = threadIdx.x;
  const int wave = t >> 6, lane = t & 63;
  const int lr = lane & 15, lg = lane >> 4;
  const int q0 = blockIdx.x * 128, h = blockIdx.y, sp = blockIdx.z;
  const int k0 = sp * KPW;
  const int r0 = t >> 3, s0 = (t & 7) * 8;            // chunk coords (2/thread)
  const int r1 = (t + 256) >> 3, s1 = s0;
  const int colK = DD + h * 64;

  // Q fragments: 4 direct loads, resident for the whole kernel
  bf16x8 aq[2][2];
#pragma unroll
  for (int mt = 0; mt < 2; ++mt)
#pragma unroll
    for (int z = 0; z < 2; ++z)
      aq[mt][z] = *reinterpret_cast<const bf16x8*>(
          QK + (q0 + wave * 32 + mt * 16 + lr) * HW + h * 64 + z * 32 + lg * 8);

  // prologue: stage chunk 0
  *reinterpret_cast<uint4*>(&Ks[0][r0 * LDA + s0]) =
      *reinterpret_cast<const uint4*>(QK + (k0 + r0) * HW + colK + s0);
  *reinterpret_cast<uint4*>(&Ks[0][r1 * LDA + s1]) =
      *reinterpret_cast<const uint4*>(QK + (k0 + r1) * HW + colK + s1);
  __syncthreads();

  float m[2][4], l[2][4];
#pragma unroll
  for (int mt = 0; mt < 2; ++mt)
#pragma unroll
    for (int r = 0; r < 4; ++r) { m[mt][r] = -3.0e38f; l[mt][r] = 0.0f; }

  for (int ci = 0; ci < NCH; ++ci) {
    const int cur = ci & 1;
    uint4 n0, n1;
    if (ci < NCH - 1) {
      int kc = k0 + (ci + 1) * 64;
      n0 = *reinterpret_cast<const uint4*>(QK + (kc + r0) * HW + colK + s0);
      n1 = *reinterpret_cast<const uint4*>(QK + (kc + r1) * HW + colK + s1);
    }
    bf16x8 b[4][2];
#pragma unroll
    for (int nt = 0; nt < 4; ++nt)
#pragma unroll
      for (int z = 0; z < 2; ++z)
        b[nt][z] = *reinterpret_cast<const bf16x8*>(&Ks[cur][(nt * 16 + lr) * LDA + z * 32 + lg * 8]);

    f32x4 s[2][4] = {};
#pragma unroll
    for (int mt = 0; mt < 2; ++mt)
#pragma unroll
      for (int nt = 0; nt < 4; ++nt)
#pragma unroll
        for (int z = 0; z < 2; ++z)
          s[mt][nt] = __builtin_amdgcn_mfma_f32_16x16x32_bf16(aq[mt][z], b[nt][z], s[mt][nt], 0, 0, 0);

    // per-lane online update (scores already in base-2 units)
#pragma unroll
    for (int mt = 0; mt < 2; ++mt)
#pragma unroll
      for (int r = 0; r < 4; ++r) {
        float v0 = s[mt][0][r], v1 = s[mt][1][r], v2 = s[mt][2][r], v3 = s[mt][3][r];
        float cm = fmaxf(fmaxf(v0, v1), fmaxf(v2, v3));
        float mn = fmaxf(m[mt][r], cm);
        float p = exp2g(v0 - mn) + exp2g(v1 - mn) +
                  exp2g(v2 - mn) + exp2g(v3 - mn);
        l[mt][r] = l[mt][r] * exp2g(m[mt][r] - mn) + p;
        m[mt][r] = mn;
      }
    if (ci < NCH - 1) {
      *reinterpret_cast<uint4*>(&Ks[cur ^ 1][r0 * LDA + s0]) = n0;
      *reinterpret_cast<uint4*>(&Ks[cur ^ 1][r1 * LDA + s1]) = n1;
      __syncthreads();
    }
  }
  // butterfly merge across the 16 lr-lanes (lg bits untouched)
#pragma unroll
  for (int msk = 1; msk <= 8; msk <<= 1) {
#pragma unroll
    for (int mt = 0; mt < 2; ++mt)
#pragma unroll
      for (int r = 0; r < 4; ++r) {
        float mo = __shfl_xor(m[mt][r], msk);
        float lo = __shfl_xor(l[mt][r], msk);
        float mn = fmaxf(m[mt][r], mo);
        l[mt][r] = l[mt][r] * exp2g(m[mt][r] - mn) + lo * exp2g(mo - mn);
        m[mt][r] = mn;
      }
  }
  if (lr == 0) {
#pragma unroll
    for (int mt = 0; mt < 2; ++mt)
#pragma unroll
      for (int r = 0; r < 4; ++r) {
        int q = q0 + wave * 32 + mt * 16 + lg * 4 + r;
        part[(sp * HH + h) * NN + q] = make_float2(m[mt][r], l[mt][r]);
      }
  }
}

// ---------------- Kernel 3: merge splits + global sum ------------------------
// 24 blocks x 1024 thr, one row each; out was zeroed by proj_kernel.
__global__ __launch_bounds__(1024) void reduce_kernel(
    const float2* __restrict__ part, float* __restrict__ out) {
  const int t = threadIdx.x;
  const int row = blockIdx.x * 1024 + t;         // 0..24575 = (h*2048+q)
  float2 p0 = part[row];
  float2 p1 = part[NROWS + row];
  float2 p2 = part[2 * NROWS + row];
  float2 p3 = part[3 * NROWS + row];
  float mm = fmaxf(fmaxf(p0.x, p1.x), fmaxf(p2.x, p3.x));
  float ll = p0.y * exp2g(p0.x - mm) + p1.y * exp2g(p1.x - mm) +
             p2.y * exp2g(p2.x - mm) + p3.y * exp2g(p3.x - mm);
  float lse = mm + log2g(ll);                    // base-2 lse
#pragma unroll
  for (int msk = 1; msk <= 32; msk <<= 1)
    lse += __shfl_xor(lse, msk);
  __shared__ float wsum[16];
  if ((t & 63) == 0) wsum[t >> 6] = lse;
  __syncthreads();
  if (t == 0) {
    float s = 0.0f;
#pragma unroll
    for (int i = 0; i < 16; ++i) s += wsum[i];
    atomicAdd(out, -5.545177444479562f * s);     // -(1/beta)*ln2 * sum(lse2)
  }
}

// ---------------- launch -----------------------------------------------------
extern "C" void kernel_launch(void* const* d_in, const int* in_sizes, int n_in,
                              void* d_out, int out_size, void* d_ws, size_t ws_size,
                              hipStream_t stream) {
  const float* g  = (const float*)d_in[0];
  const float* Wq = (const float*)d_in[1];
  const float* Wk = (const float*)d_in[2];
  float* out = (float*)d_out;

  __hip_bfloat16* QK = (__hip_bfloat16*)d_ws;                      // [2048][1536] (6.3 MB)
  float2* part = (float2*)((char*)d_ws + (size_t)NN * HW * 2);     // [4][12][2048] (786 KB)

  proj_kernel<<<384, 256, 0, stream>>>(g, Wq, Wk, QK, out);
  attn_kernel<<<dim3(16, HH, SPLITS), 256, 0, stream>>>(QK, part);
  reduce_kernel<<<24, 1024, 0, stream>>>(part, out);
}